// Round 1
// baseline (118.319 us; speedup 1.0000x reference)
//
#include <hip/hip_runtime.h>

typedef _Float16 half8 __attribute__((ext_vector_type(8)));
typedef float floatx4 __attribute__((ext_vector_type(4)));

static constexpr int NB  = 32;    // batches
static constexpr int NP  = 4096;  // points per batch
static constexpr int DD  = 128;   // dim
static constexpr int KC  = 64;    // clusters
static constexpr int TN  = 64;    // points per tile
static constexpr int TPB = 4;     // tiles per block
static constexpr int SLOTS = NP / (TPB * TN);   // 16 slot-blocks per batch
static constexpr int STP = 72;    // sxt / sat pitch (halfwords).  NOTE: stride
                                  // 36 dwords ≡ 4 (mod 32 banks) is what makes
                                  // the XOR-swizzled b128 reads 2-way-max; do
                                  // not "optimize" to 64.

#define ALPHA_  100.0f
#define LOG2E_  1.44269504088896f

// Workgroup barrier that waits ONLY on LDS (lgkmcnt), leaving prefetched
// global loads in flight. __syncthreads() would emit s_waitcnt vmcnt(0)
// and drain the prefetch on the critical path.
#define LGKM_BARRIER() asm volatile("s_waitcnt lgkmcnt(0)\ns_barrier" ::: "memory")

// Kernel 1: distances -> softmax -> vlad partial, accumulated into the
// per-batch result with device-scope fp32 atomics (vfull/csum are zeroed by a
// memset node in the graph).  Same atomic-instruction count per lane (32) as
// the old plain-store epilogue, but kills the 16.8 MB vp round-trip and the
// separate reduce kernel.
__global__ __launch_bounds__(256, 2)
void vlad_main(const float* __restrict__ xg, const float* __restrict__ cg,
               float* __restrict__ vfull, float* __restrict__ csum)
{
    __shared__ __align__(16) _Float16 sxt[2][DD][STP];  // x^T [d][n^swz], dbuf
    __shared__ __align__(16) _Float16 sat[2][KC][STP];  // a^T [k][n^swz], dbuf
    __shared__ float sc2[KC];

    const int tid  = threadIdx.x;
    const int lane = tid & 63;
    const int w    = tid >> 6;
    const int l15  = lane & 15;
    const int quad = lane >> 4;
    const int b    = blockIdx.y;
    const int s    = blockIdx.x;          // slot within batch
    const float* xb = xg + (size_t)b * NP * DD;

    const int nloc = w*16 + l15;
    const int scol = nloc ^ (quad << 4);
    const float* xpt = xb + (size_t)(s*TPB*TN + nloc)*DD + quad*8;

    // ---- issue x tile-0 loads FIRST (cold HBM; hide under centroid prep) ----
    float4 fa[4], fb[4];
#pragma unroll
    for (int ks = 0; ks < 4; ++ks) {
        fa[ks] = *(const float4*)(xpt + ks*32);
        fb[ks] = *(const float4*)(xpt + ks*32 + 4);
    }

    // ---- centroid prep: fp16 hi-frags in registers; c2 (fp32, exact) via
    //      cross-quad shuffles of the same loads ----
    half8 chi[4][4]; // [mt][ks]: lane holds C[mt*16+l15][ks*32+quad*8 .. +7]
    float c2p[4];
#pragma unroll
    for (int mt = 0; mt < 4; ++mt) {
        c2p[mt] = 0.f;
#pragma unroll
        for (int ks = 0; ks < 4; ++ks) {
            const float* p = cg + (mt*16 + l15)*DD + ks*32 + quad*8;
            float4 a  = *(const float4*)p;
            float4 bb = *(const float4*)(p + 4);
            half8 h;
            h[0]=(_Float16)a.x;  h[1]=(_Float16)a.y;  h[2]=(_Float16)a.z;  h[3]=(_Float16)a.w;
            h[4]=(_Float16)bb.x; h[5]=(_Float16)bb.y; h[6]=(_Float16)bb.z; h[7]=(_Float16)bb.w;
            chi[mt][ks] = h;
            c2p[mt] += a.x*a.x + a.y*a.y + a.z*a.z + a.w*a.w
                     + bb.x*bb.x + bb.y*bb.y + bb.z*bb.z + bb.w*bb.w;
        }
    }
#pragma unroll
    for (int mt = 0; mt < 4; ++mt) {
        // quads hold disjoint column segments of the SAME row mt*16+l15
        float s2 = c2p[mt];
        s2 += __shfl_xor(s2, 16);
        s2 += __shfl_xor(s2, 32);
        if (quad == 0 && w == 0) sc2[mt*16 + l15] = s2;
    }
    LGKM_BARRIER();   // sc2 ready (x tile-0 loads stay in flight)

    floatx4 acc2[8];   // vlad partial: row k = w*16+quad*4+r, col d = nt*16+l15
#pragma unroll
    for (int i = 0; i < 8; ++i) acc2[i] = (floatx4){0.f, 0.f, 0.f, 0.f};
    floatx4 accs = (floatx4){0.f, 0.f, 0.f, 0.f};  // colsum via ones-column MFMA

    half8 onesf;       // B[point][col] = (col==0)
#pragma unroll
    for (int j = 0; j < 8; ++j) onesf[j] = (_Float16)((l15 == 0) ? 1.0f : 0.0f);

#pragma unroll
    for (int tt = 0; tt < TPB; ++tt) {
        const int pb = tt & 1;   // LDS buffer parity

        // ---- convert staged fp32 -> fp16 frags; per-lane ssq ----
        half8 xf[4];
        float ssq = 0.f;
#pragma unroll
        for (int ks = 0; ks < 4; ++ks) {
            half8 h;
            h[0]=(_Float16)fa[ks].x; h[1]=(_Float16)fa[ks].y;
            h[2]=(_Float16)fa[ks].z; h[3]=(_Float16)fa[ks].w;
            h[4]=(_Float16)fb[ks].x; h[5]=(_Float16)fb[ks].y;
            h[6]=(_Float16)fb[ks].z; h[7]=(_Float16)fb[ks].w;
            xf[ks] = h;
            ssq += fa[ks].x*fa[ks].x + fa[ks].y*fa[ks].y + fa[ks].z*fa[ks].z + fa[ks].w*fa[ks].w
                 + fb[ks].x*fb[ks].x + fb[ks].y*fb[ks].y + fb[ks].z*fb[ks].z + fb[ks].w*fb[ks].w;
        }

        // ---- prefetch next tile; stays in flight across the lgkm barrier ----
        if (tt + 1 < TPB) {
            const float* xr = xpt + (size_t)(tt + 1) * TN * DD;
#pragma unroll
            for (int ks = 0; ks < 4; ++ks) {
                fa[ks] = *(const float4*)(xr + ks*32);
                fb[ks] = *(const float4*)(xr + ks*32 + 4);
            }
        }

        // ---- write x^T (swizzled; 2-way max = free) ----
#pragma unroll
        for (int ks = 0; ks < 4; ++ks)
#pragma unroll
            for (int j = 0; j < 8; ++j)
                sxt[pb][ks*32 + quad*8 + j][scol] = xf[ks][j];

        // ---- GEMM1: S^T[cluster][point], c fp16 ----
        floatx4 acc1[4];
#pragma unroll
        for (int mt = 0; mt < 4; ++mt) acc1[mt] = (floatx4){0.f, 0.f, 0.f, 0.f};
#pragma unroll
        for (int ks = 0; ks < 4; ++ks)
#pragma unroll
            for (int mt = 0; mt < 4; ++mt)
                acc1[mt] = __builtin_amdgcn_mfma_f32_16x16x32_f16(chi[mt][ks], xf[ks], acc1[mt], 0, 0, 0);
        ssq += __shfl_xor(ssq, 16);
        ssq += __shfl_xor(ssq, 32);

        // ---- softmax over 64 clusters for this lane's point ----
        float dist[4][4];
#pragma unroll
        for (int mt = 0; mt < 4; ++mt) {
            floatx4 c2v = *(const floatx4*)&sc2[mt*16 + quad*4];
#pragma unroll
            for (int r = 0; r < 4; ++r) {
                float d2 = ssq + c2v[r] - 2.f*acc1[mt][r];
                dist[mt][r] = sqrtf(fmaxf(d2, 0.f));
            }
        }
        float dmin = dist[0][0];
#pragma unroll
        for (int mt = 0; mt < 4; ++mt)
#pragma unroll
            for (int r = 0; r < 4; ++r) dmin = fminf(dmin, dist[mt][r]);
        dmin = fminf(dmin, __shfl_xor(dmin, 16));
        dmin = fminf(dmin, __shfl_xor(dmin, 32));
        float pv[4][4];
        float psum = 0.f;
#pragma unroll
        for (int mt = 0; mt < 4; ++mt)
#pragma unroll
            for (int r = 0; r < 4; ++r) {
                float e = exp2f((dmin - dist[mt][r]) * (ALPHA_ * LOG2E_));
                pv[mt][r] = e; psum += e;
            }
        psum += __shfl_xor(psum, 16);
        psum += __shfl_xor(psum, 32);
        float invs = 1.0f / psum;
#pragma unroll
        for (int mt = 0; mt < 4; ++mt)
#pragma unroll
            for (int r = 0; r < 4; ++r)
                sat[pb][mt*16 + quad*4 + r][scol] = (_Float16)(pv[mt][r] * invs);

        LGKM_BARRIER();   // sxt/sat[pb] visible; prefetch loads NOT drained

        // ---- GEMM2: vlad[k][d] += a^T · x ; colsum via ones column ----
        // Double buffer: buf[pb] can't be rewritten until all waves pass the
        // NEXT tile's barrier, which postdates every read below.
#pragma unroll
        for (int ks2 = 0; ks2 < 2; ++ks2) {
            const int nbase = ks2*32 + quad*8;
            half8 af = *(const half8*)&sat[pb][w*16 + l15][nbase ^ ((l15 >> 2) << 4)];
            accs = __builtin_amdgcn_mfma_f32_16x16x32_f16(af, onesf, accs, 0, 0, 0);
#pragma unroll
            for (int nt = 0; nt < 8; ++nt) {
                const int d = nt*16 + l15;
                half8 bf = *(const half8*)&sxt[pb][d][nbase ^ (((d >> 3) & 3) << 4)];
                acc2[nt] = __builtin_amdgcn_mfma_f32_16x16x32_f16(af, bf, acc2[nt], 0, 0, 0);
            }
        }
    }

    // ---- epilogue: device-scope atomic accumulation into per-batch result.
    // Same address pattern as the old plain stores (4×64B segments per wave
    // instruction); 16 slot-blocks per batch contribute to each element. ----
    float* vb = vfull + (size_t)b * (KC*DD);
#pragma unroll
    for (int nt = 0; nt < 8; ++nt)
#pragma unroll
        for (int r = 0; r < 4; ++r) {
            int k = w*16 + quad*4 + r;
            int d = nt*16 + l15;
            atomicAdd(&vb[k*DD + d], acc2[nt][r]);
        }
    if (l15 == 0) {
#pragma unroll
        for (int r = 0; r < 4; ++r)
            atomicAdd(&csum[(size_t)b*KC + w*16 + quad*4 + r], accs[r]);
    }
}

// Kernel 2 (final): subtract colsum*c, compute batch L2 norm, normalize, write.
// One block per batch; each thread owns 32 elements held in registers across
// the reduce so vfull is read exactly once.
__global__ __launch_bounds__(256)
void vlad_finalize(const float* __restrict__ vfull, const float* __restrict__ csum,
                   const float* __restrict__ cg, float* __restrict__ out)
{
    __shared__ float scs[KC];
    __shared__ float red[4];
    const int b   = blockIdx.x;
    const int tid = threadIdx.x;

    if (tid < KC) scs[tid] = csum[(size_t)b*KC + tid];
    __syncthreads();

    const float* vb = vfull + (size_t)b*(KC*DD);
    float4 v[8];
    float ss = 0.f;
#pragma unroll
    for (int i = 0; i < 8; ++i) {
        const int idx = i*1024 + tid*4;   // 4 consecutive elements, same cluster
        float4 a  = *(const float4*)(vb + idx);
        float4 cv = *(const float4*)(cg + idx);
        float cs  = scs[idx >> 7];
        a.x -= cs*cv.x; a.y -= cs*cv.y; a.z -= cs*cv.z; a.w -= cs*cv.w;
        v[i] = a;
        ss += a.x*a.x + a.y*a.y + a.z*a.z + a.w*a.w;
    }
#pragma unroll
    for (int m = 1; m < 64; m <<= 1) ss += __shfl_xor(ss, m);
    if ((tid & 63) == 0) red[tid >> 6] = ss;
    __syncthreads();
    float tot = red[0] + red[1] + red[2] + red[3];
    float scale = 1.0f / fmaxf(sqrtf(tot), 1e-12f);
#pragma unroll
    for (int i = 0; i < 8; ++i) {
        const int idx = i*1024 + tid*4;
        float4 a = v[i];
        a.x *= scale; a.y *= scale; a.z *= scale; a.w *= scale;
        *(float4*)(out + (size_t)b*(KC*DD) + idx) = a;
    }
}

extern "C" void kernel_launch(void* const* d_in, const int* in_sizes, int n_in,
                              void* d_out, int out_size, void* d_ws, size_t ws_size,
                              hipStream_t stream)
{
    (void)in_sizes; (void)n_in; (void)out_size; (void)ws_size;
    const float* x = (const float*)d_in[0];
    const float* c = (const float*)d_in[1];
    float* out   = (float*)d_out;
    float* vfull = (float*)d_ws;                             // [32][64][128] = 1 MB
    float* csum  = vfull + (size_t)NB*KC*DD;                 // [32][64] = 8 KB

    // zero the atomic accumulators (graph-capturable memset node, ~1.06 MB)
    hipMemsetAsync(d_ws, 0, ((size_t)NB*KC*DD + (size_t)NB*KC)*sizeof(float), stream);

    vlad_main<<<dim3(SLOTS, NB), 256, 0, stream>>>(x, c, vfull, csum);
    vlad_finalize<<<NB, 256, 0, stream>>>(vfull, csum, c, out);
}